// Round 1
// baseline (274.598 us; speedup 1.0000x reference)
//
#include <hip/hip_runtime.h>

// VQ eval: x[131072,64] fp32, w[1024,64] fp32.
// out concat: x_q (8388608 f32) | loss (1 f32) | indices (131072 f32).
//
// Screen = bf16 MFMA GEMM, K=192 split trick: A_ext=[x_h|x_l|x_h], B_ext=[w_h|w_h|w_l]
// (bf16 RNE hi + residual), score = en - 2*dot, |err|~1e-7. Top-2 gap < MARGIN ->
// idx written as -(id+1) (float); k_recheck re-resolves flagged tokens with the
// np-fp32-replicated scan (sequential-k fp32 FMA == BLAS sgemm microkernel,
// quantized combine, first-index ties).
//
// R8: chunk = 64 codes. B buffer 24 KB, en[1024] LDS-resident (4 KB), total LDS
// 28672 B. B_ext pre-permuted by k_prep into fragment order so global_load_lds
// (lane-linear) -> hot-loop ds_read_b128 at base+lane*16, conflict-free.
//
// R9 (this round): k_screen was VALU-issue-bound (VALUBusy 56% > MfmaUtil 29.5%);
// the top-2 compare/select chain cost ~7 VALU/score x 512 scores/thread.
//  (a) mantissa-packed argmin: code id (10 bits) packed into low mantissa of the
//      score; top-2 update becomes fmin + fmed3 (2 instr), index selects gone.
//      Packing perturbs scores <= 1023 ulp (~7.6e-6 at |s|<0.125); any token whose
//      packed argmin could differ from the true fp32 argmin has packed gap
//      <= 2*eps ~ 1.6e-5 < MARGIN=3e-5 -> flagged -> k_recheck resolves exactly.
//      Ties (distinct jg => distinct packed values) land within margin -> flagged
//      -> first-index rule preserved by recheck.
//  (b) __launch_bounds__(256,5): 5 blocks/CU (LDS 5*28672=140 KiB <= 160 KiB,
//      VGPR 64 << 102 cap) to cover per-chunk barrier drains.

#define N_TOK   131072
#define DIM     64
#define KCODES  1024
#define MARGIN  3e-5f
#define LOSS_POS ((size_t)8388608)
#define EN_OFF_F 98304           // w_ext = 98304 uints (16 chunks * 24 ksteps * 64 lanes * 4)

typedef __attribute__((ext_vector_type(8))) short  short8;
typedef __attribute__((ext_vector_type(4))) float  float4v;

__device__ __forceinline__ unsigned bf16rne(float f) {
    unsigned u = __float_as_uint(f);
    return (u + 0x7FFFu + ((u >> 16) & 1u)) >> 16;
}
__device__ __forceinline__ float bf16tof(unsigned h) { return __uint_as_float(h << 16); }

// ---------------- K0: w_ext in chunk-64 fragment order + en[1024] + loss zero
__global__ __launch_bounds__(256) void k_prep(const float* __restrict__ w,
                                              float* __restrict__ out) {
    if (blockIdx.x < 96) {
        const int g    = blockIdx.x * 256 + threadIdx.x;   // 0..24575
        const int lane = g & 63;
        const int fs   = g >> 6;                            // c*24 + nt*6 + ks
        const int c = fs / 24, r = fs % 24, nt = r / 6, ks = r % 6;
        const int j    = c * 64 + nt * 16 + (lane & 15);
        const int quad = lane >> 4;
        const int kk   = ks * 32 + quad * 8;                // 0..184
        const bool hi  = (kk < 128);
        const int k0   = hi ? (kk & 63) : (kk - 128);
        const float4* src = (const float4*)(w + (size_t)j * DIM + k0);
        float4 v0 = src[0], v1 = src[1];
        float f[8] = {v0.x, v0.y, v0.z, v0.w, v1.x, v1.y, v1.z, v1.w};
        unsigned o[4];
#pragma unroll
        for (int p = 0; p < 4; ++p) {
            unsigned h0 = bf16rne(f[2 * p]), h1 = bf16rne(f[2 * p + 1]);
            if (hi) o[p] = h0 | (h1 << 16);
            else {
                unsigned l0 = bf16rne(f[2 * p]     - bf16tof(h0));
                unsigned l1 = bf16rne(f[2 * p + 1] - bf16tof(h1));
                o[p] = l0 | (l1 << 16);
            }
        }
        *(uint4*)((unsigned*)out + (size_t)g * 4) = make_uint4(o[0], o[1], o[2], o[3]);
    } else {
        const int row = (blockIdx.x - 96) * 256 + threadIdx.x;  // 0..1023
        const float* wr = w + (size_t)row * DIM;
        double en = 0.0;
#pragma unroll 8
        for (int k = 0; k < DIM; ++k) { double v = wr[k]; en += v * v; }
        out[EN_OFF_F + row] = (float)en;
        if (row == 0) out[LOSS_POS] = 0.0f;
    }
}

// ---------------- K1: MFMA screen + fused top-2, float idx out (negative = flagged)
__global__ __launch_bounds__(256, 5) void k_screen(
    const float* __restrict__ x, const float* __restrict__ outsrc,
    float* __restrict__ idxf)
{
    __shared__ __align__(16) unsigned char smem[28672];  // [0,24576) A->B | [24576,28672) en
    unsigned* smemU = (unsigned*)smem;
    const float* en_s = (const float*)(smem + 24576);

    const int tid  = threadIdx.x;
    const int lane = tid & 63;
    const int wv   = tid >> 6;
    const int col  = lane & 15;
    const int quad = (lane >> 4) & 3;
    const int tokBase = blockIdx.x * 128;

    // ---- stage en[1024] once (resident for the whole kernel)
    __builtin_amdgcn_global_load_lds(
        (const __attribute__((address_space(1))) void*)
            ((const unsigned char*)(outsrc + EN_OFF_F) + tid * 16),
        (__attribute__((address_space(3))) void*)(smem + 24576 + tid * 16),
        16, 0, 0);

    // ---- stage A_ext in two 64-token passes; owning waves grab their fragments
    short8 afrag[2][6];
    for (int pass = 0; pass < 2; ++pass) {
        const int row = tid >> 2, seg = tid & 3;
        const float4* xr = (const float4*)(x + (size_t)(tokBase + pass * 64 + row) * DIM + seg * 16);
        unsigned* rb = smemU + row * 96 + seg * 8;
#pragma unroll
        for (int q = 0; q < 4; ++q) {
            float4 v = xr[q];
            unsigned hx = bf16rne(v.x), hy = bf16rne(v.y);
            unsigned hz = bf16rne(v.z), hw = bf16rne(v.w);
            unsigned h01 = hx | (hy << 16), h23 = hz | (hw << 16);
            unsigned l01 = bf16rne(v.x - bf16tof(hx)) | (bf16rne(v.y - bf16tof(hy)) << 16);
            unsigned l23 = bf16rne(v.z - bf16tof(hz)) | (bf16rne(v.w - bf16tof(hw)) << 16);
            rb[2 * q] = h01;      rb[2 * q + 1] = h23;        // x_h  (k 0..63)
            rb[32 + 2 * q] = l01; rb[32 + 2 * q + 1] = l23;   // x_l  (k 64..127)
            rb[64 + 2 * q] = h01; rb[64 + 2 * q + 1] = h23;   // x_h  (k 128..191)
        }
        __syncthreads();
        if ((wv >> 1) == pass) {
#pragma unroll
            for (int mt = 0; mt < 2; ++mt)
#pragma unroll
                for (int ks = 0; ks < 6; ++ks)
                    afrag[mt][ks] = *(const short8*)(smem
                        + ((wv & 1) * 32 + mt * 16 + col) * 384 + ks * 64 + quad * 16);
        }
        __syncthreads();   // reads done before next pass / B staging overwrites
    }

    // m1/m2 hold PACKED scores: low 10 mantissa bits = code id. m1 <= m2 invariant.
    float m1[8], m2[8];
#pragma unroll
    for (int i = 0; i < 8; ++i) { m1[i] = 3.4e38f; m2[i] = 3.4e38f; }

    float4v acc[2][4];
#pragma unroll
    for (int mt = 0; mt < 2; ++mt)
#pragma unroll
        for (int nt = 0; nt < 4; ++nt)
            acc[mt][nt] = (float4v){0.f, 0.f, 0.f, 0.f};

    auto epi = [&](int c) {
        const int jbase = c * 64 + col;
#pragma unroll
        for (int nt = 0; nt < 4; ++nt) {
            const unsigned jg = (unsigned)(jbase + nt * 16);
            const float ec = en_s[jg];
#pragma unroll
            for (int mt = 0; mt < 2; ++mt)
#pragma unroll
                for (int r = 0; r < 4; ++r) {
                    const int t = mt * 4 + r;
                    float s = fmaf(acc[mt][nt][r], -2.0f, ec);
                    // pack code id into low 10 mantissa bits (v_and_or_b32)
                    float p = __uint_as_float((__float_as_uint(s) & 0xFFFFFC00u) | jg);
                    // top-2 update in 2 instr: med3(m1,m2,p) = new second-min (m1<=m2)
                    m2[t] = __builtin_amdgcn_fmed3f(m1[t], m2[t], p);
                    m1[t] = fminf(m1[t], p);
                    acc[mt][nt][r] = 0.0f;
                }
        }
    };

    const unsigned char* wext = (const unsigned char*)outsrc;

    for (int c = 0; c < 16; ++c) {
        // async-stage B chunk c (64 codes x 384 B = 24576 B = exactly 6 loads/thread)
        {
            const unsigned char* gsrc = wext + c * 24576 + tid * 16;
            unsigned char*       ldst = smem + tid * 16;
#pragma unroll
            for (int it = 0; it < 6; ++it) {
                __builtin_amdgcn_global_load_lds(
                    (const __attribute__((address_space(1))) void*)(gsrc + it * 4096),
                    (__attribute__((address_space(3))) void*)(ldst + it * 4096),
                    16, 0, 0);
            }
        }
        if (c > 0) epi(c - 1);      // overlap previous epilogue with load latency
        __syncthreads();            // B chunk resident

#pragma unroll
        for (int ks = 0; ks < 6; ++ks) {
            short8 b[4];
#pragma unroll
            for (int nt = 0; nt < 4; ++nt)
                b[nt] = *(const short8*)(smem + ((nt * 6 + ks) * 64 + lane) * 16);
#pragma unroll
            for (int nt = 0; nt < 4; ++nt) {
                acc[0][nt] = __builtin_amdgcn_mfma_f32_16x16x32_bf16(afrag[0][ks], b[nt], acc[0][nt], 0, 0, 0);
                acc[1][nt] = __builtin_amdgcn_mfma_f32_16x16x32_bf16(afrag[1][ks], b[nt], acc[1][nt], 0, 0, 0);
            }
        }
        __syncthreads();            // all B reads done before next chunk's staging
    }
    epi(15);

    // ---- merge top-2 across the 16 C/D columns (lane bits 0..3).
    // Packed values are globally distinct (distinct code ids), so plain
    // min/second-min merge is exact; near-ties land within MARGIN -> flagged.
#pragma unroll
    for (int m = 1; m <= 8; m <<= 1) {
#pragma unroll
        for (int t = 0; t < 8; ++t) {
            float o1 = __shfl_xor(m1[t], m, 64);
            float o2 = __shfl_xor(m2[t], m, 64);
            m2[t] = fminf(fminf(m2[t], o2), fmaxf(m1[t], o1));
            m1[t] = fminf(m1[t], o1);
        }
    }
    if (col == 0) {
#pragma unroll
        for (int t = 0; t < 8; ++t) {
            const int mt = t >> 2, r = t & 3;
            const int tok = tokBase + wv * 32 + mt * 16 + quad * 4 + r;
            const int id  = (int)(__float_as_uint(m1[t]) & 1023u);
            idxf[tok] = (m2[t] - m1[t] < MARGIN) ? -(float)(id + 1) : (float)id;
        }
    }
}

// ---------------- K2: np-fp32-replicated rescan of flagged tokens (proven body)
__global__ __launch_bounds__(256) void k_recheck(
    const float* __restrict__ x, const float* __restrict__ w,
    float* __restrict__ idxf)
{
    __shared__ int   nflag;
    __shared__ int   flist[256];
    __shared__ float xf[DIM];
    __shared__ float rd[256];
    __shared__ int   rj[256];

    const int tid = threadIdx.x;
    const int tok = blockIdx.x * 256 + tid;
    if (tid == 0) nflag = 0;
    __syncthreads();
    if (idxf[tok] < 0.0f) { int p = atomicAdd(&nflag, 1); flist[p] = tok; }
    __syncthreads();
    const int nf = nflag;

    for (int f = 0; f < nf; ++f) {
        const int ft = flist[f];
        if (tid < DIM) xf[tid] = x[(size_t)ft * DIM + tid];
        __syncthreads();

        double xnd = 0.0;
        for (int k = 0; k < DIM; ++k) { double xv = (double)xf[k]; xnd += xv * xv; }
        const float xn = (float)xnd;

        float dbest = 3.4e38f; int jbest = 0;
#pragma unroll
        for (int jj = 0; jj < KCODES / 256; ++jj) {
            const int j = tid + jj * 256;
            const float* wr = w + (size_t)j * DIM;
            double end = 0.0;
            float  cacc = 0.0f;   // sequential-k fp32 FMA == BLAS sgemm microkernel
            for (int k = 0; k < DIM; ++k) {
                float wv2 = wr[k];
                end += (double)wv2 * wv2;
                cacc = __fmaf_rn(xf[k], wv2, cacc);
            }
            float T = __fadd_rn(xn, (float)end);
            float d = __fsub_rn(T, __fmul_rn(2.0f, cacc));
            if (d < dbest) { dbest = d; jbest = j; }   // strict <: first index
        }
        rd[tid] = dbest; rj[tid] = jbest;
        __syncthreads();
        for (int off = 128; off > 0; off >>= 1) {
            if (tid < off) {
                float od = rd[tid + off]; int oj = rj[tid + off];
                if (od < rd[tid] || (od == rd[tid] && oj < rj[tid])) {
                    rd[tid] = od; rj[tid] = oj;
                }
            }
            __syncthreads();
        }
        if (tid == 0) idxf[ft] = (float)rj[0];
        __syncthreads();
    }
}

// ---------------- K3: gather x_q + loss sum (reads final float idx)
__global__ __launch_bounds__(256) void k_gather(
    const float* __restrict__ x, const float* __restrict__ w,
    const float* __restrict__ idxf, float* __restrict__ out)
{
    const float4* x4 = (const float4*)x;
    const float4* w4 = (const float4*)w;
    float4*       o4 = (float4*)out;
    const int total4 = N_TOK * (DIM / 4);
    const int stride = gridDim.x * blockDim.x;
    double acc = 0.0;
    for (int i = blockIdx.x * blockDim.x + threadIdx.x; i < total4; i += stride) {
        int tok = i >> 4, c = i & 15;
        int id  = (int)idxf[tok];
        float4 xv = x4[i];
        float4 wv = w4[(size_t)id * (DIM / 4) + c];
        o4[i] = wv;
        float dx = xv.x - wv.x, dy = xv.y - wv.y, dz = xv.z - wv.z, dw = xv.w - wv.w;
        acc += (double)dx * dx + (double)dy * dy + (double)dz * dz + (double)dw * dw;
    }
    __shared__ double r[256];
    r[threadIdx.x] = acc;
    __syncthreads();
    for (int off = 128; off > 0; off >>= 1) {
        if (threadIdx.x < off) r[threadIdx.x] += r[threadIdx.x + off];
        __syncthreads();
    }
    if (threadIdx.x == 0) unsafeAtomicAdd(out + LOSS_POS, (float)r[0]);
}

// ---------------- K4: loss scale only
__global__ void k_loss(float* __restrict__ out) {
    out[LOSS_POS] = out[LOSS_POS] * 1.25f / 8388608.0f;
}

extern "C" void kernel_launch(void* const* d_in, const int* in_sizes, int n_in,
                              void* d_out, int out_size, void* d_ws, size_t ws_size,
                              hipStream_t stream) {
    const float* x = (const float*)d_in[0];
    const float* w = (const float*)d_in[1];
    float* out = (float*)d_out;
    float* idxf = out + LOSS_POS + 1;

    k_prep<<<100, 256, 0, stream>>>(w, out);
    k_screen<<<N_TOK / 128, 256, 0, stream>>>(x, out, idxf);
    k_recheck<<<N_TOK / 256, 256, 0, stream>>>(x, w, idxf);
    k_gather<<<2048, 256, 0, stream>>>(x, w, idxf, out);
    k_loss<<<1, 1, 0, stream>>>(out);
}

// Round 2
// 217.979 us; speedup vs baseline: 1.2597x; 1.2597x over previous
//
#include <hip/hip_runtime.h>

// VQ eval: x[131072,64] fp32, w[1024,64] fp32.
// out concat: x_q (8388608 f32) | loss (1 f32) | indices (131072 f32).
//
// Screen = bf16 MFMA GEMM, K=192 split trick: A_ext=[x_h|x_l|x_h], B_ext=[w_h|w_h|w_l]
// (bf16 RNE hi + residual), score = en - 2*dot, |err|~1e-7. Top-2 gap < MARGIN ->
// idx written as -(id+1) (float); k_recheck re-resolves flagged tokens with the
// np-fp32-replicated scan (sequential-k fp32 FMA == BLAS sgemm microkernel,
// quantized combine, first-index ties).
//
// R8: chunk = 64 codes. B buffer 24 KB, en[1024] LDS-resident (4 KB), total LDS
// 28672 B. B_ext pre-permuted by k_prep into fragment order so global_load_lds
// (lane-linear) -> hot-loop ds_read_b128 at base+lane*16, conflict-free.
//
// R9 lesson (REVERTED): __launch_bounds__(256,5) caps VGPR budget at 512/5~96/wave
// (2nd arg = min waves/EU); kernel needs ~112 -> scratch spills (FETCH 20->322 MB,
// WRITE 4.6->49.7 MB, dur 74->124 us). Grid is 1024 blocks = exactly 4/CU anyway,
// so 5 was unreachable. Back to (256,4) = 128-reg budget, no spill.
//
// R10 (kept from R9): mantissa-packed argmin epilogue. Code id (10 bits) packed
// into low mantissa of the score; top-2 update becomes fmin + fmed3 (2 instr/score
// after fma+and_or), index selects and tie-branch gone (~4 VALU/score vs ~7-8).
// Packing perturbs scores <= 1023 ulp (~7.6e-6 at |s|<0.125); any token whose
// packed argmin could differ from true fp32 argmin has packed gap <= ~1.6e-5
// < MARGIN=3e-5 -> flagged -> k_recheck resolves exactly. Ties (distinct jg =>
// distinct packed values) land within margin -> flagged -> first-index preserved.

#define N_TOK   131072
#define DIM     64
#define KCODES  1024
#define MARGIN  3e-5f
#define LOSS_POS ((size_t)8388608)
#define EN_OFF_F 98304           // w_ext = 98304 uints (16 chunks * 24 ksteps * 64 lanes * 4)

typedef __attribute__((ext_vector_type(8))) short  short8;
typedef __attribute__((ext_vector_type(4))) float  float4v;

__device__ __forceinline__ unsigned bf16rne(float f) {
    unsigned u = __float_as_uint(f);
    return (u + 0x7FFFu + ((u >> 16) & 1u)) >> 16;
}
__device__ __forceinline__ float bf16tof(unsigned h) { return __uint_as_float(h << 16); }

// ---------------- K0: w_ext in chunk-64 fragment order + en[1024] + loss zero
__global__ __launch_bounds__(256) void k_prep(const float* __restrict__ w,
                                              float* __restrict__ out) {
    if (blockIdx.x < 96) {
        const int g    = blockIdx.x * 256 + threadIdx.x;   // 0..24575
        const int lane = g & 63;
        const int fs   = g >> 6;                            // c*24 + nt*6 + ks
        const int c = fs / 24, r = fs % 24, nt = r / 6, ks = r % 6;
        const int j    = c * 64 + nt * 16 + (lane & 15);
        const int quad = lane >> 4;
        const int kk   = ks * 32 + quad * 8;                // 0..184
        const bool hi  = (kk < 128);
        const int k0   = hi ? (kk & 63) : (kk - 128);
        const float4* src = (const float4*)(w + (size_t)j * DIM + k0);
        float4 v0 = src[0], v1 = src[1];
        float f[8] = {v0.x, v0.y, v0.z, v0.w, v1.x, v1.y, v1.z, v1.w};
        unsigned o[4];
#pragma unroll
        for (int p = 0; p < 4; ++p) {
            unsigned h0 = bf16rne(f[2 * p]), h1 = bf16rne(f[2 * p + 1]);
            if (hi) o[p] = h0 | (h1 << 16);
            else {
                unsigned l0 = bf16rne(f[2 * p]     - bf16tof(h0));
                unsigned l1 = bf16rne(f[2 * p + 1] - bf16tof(h1));
                o[p] = l0 | (l1 << 16);
            }
        }
        *(uint4*)((unsigned*)out + (size_t)g * 4) = make_uint4(o[0], o[1], o[2], o[3]);
    } else {
        const int row = (blockIdx.x - 96) * 256 + threadIdx.x;  // 0..1023
        const float* wr = w + (size_t)row * DIM;
        double en = 0.0;
#pragma unroll 8
        for (int k = 0; k < DIM; ++k) { double v = wr[k]; en += v * v; }
        out[EN_OFF_F + row] = (float)en;
        if (row == 0) out[LOSS_POS] = 0.0f;
    }
}

// ---------------- K1: MFMA screen + fused top-2, float idx out (negative = flagged)
__global__ __launch_bounds__(256, 4) void k_screen(
    const float* __restrict__ x, const float* __restrict__ outsrc,
    float* __restrict__ idxf)
{
    __shared__ __align__(16) unsigned char smem[28672];  // [0,24576) A->B | [24576,28672) en
    unsigned* smemU = (unsigned*)smem;
    const float* en_s = (const float*)(smem + 24576);

    const int tid  = threadIdx.x;
    const int lane = tid & 63;
    const int wv   = tid >> 6;
    const int col  = lane & 15;
    const int quad = (lane >> 4) & 3;
    const int tokBase = blockIdx.x * 128;

    // ---- stage en[1024] once (resident for the whole kernel)
    __builtin_amdgcn_global_load_lds(
        (const __attribute__((address_space(1))) void*)
            ((const unsigned char*)(outsrc + EN_OFF_F) + tid * 16),
        (__attribute__((address_space(3))) void*)(smem + 24576 + tid * 16),
        16, 0, 0);

    // ---- stage A_ext in two 64-token passes; owning waves grab their fragments
    short8 afrag[2][6];
    for (int pass = 0; pass < 2; ++pass) {
        const int row = tid >> 2, seg = tid & 3;
        const float4* xr = (const float4*)(x + (size_t)(tokBase + pass * 64 + row) * DIM + seg * 16);
        unsigned* rb = smemU + row * 96 + seg * 8;
#pragma unroll
        for (int q = 0; q < 4; ++q) {
            float4 v = xr[q];
            unsigned hx = bf16rne(v.x), hy = bf16rne(v.y);
            unsigned hz = bf16rne(v.z), hw = bf16rne(v.w);
            unsigned h01 = hx | (hy << 16), h23 = hz | (hw << 16);
            unsigned l01 = bf16rne(v.x - bf16tof(hx)) | (bf16rne(v.y - bf16tof(hy)) << 16);
            unsigned l23 = bf16rne(v.z - bf16tof(hz)) | (bf16rne(v.w - bf16tof(hw)) << 16);
            rb[2 * q] = h01;      rb[2 * q + 1] = h23;        // x_h  (k 0..63)
            rb[32 + 2 * q] = l01; rb[32 + 2 * q + 1] = l23;   // x_l  (k 64..127)
            rb[64 + 2 * q] = h01; rb[64 + 2 * q + 1] = h23;   // x_h  (k 128..191)
        }
        __syncthreads();
        if ((wv >> 1) == pass) {
#pragma unroll
            for (int mt = 0; mt < 2; ++mt)
#pragma unroll
                for (int ks = 0; ks < 6; ++ks)
                    afrag[mt][ks] = *(const short8*)(smem
                        + ((wv & 1) * 32 + mt * 16 + col) * 384 + ks * 64 + quad * 16);
        }
        __syncthreads();   // reads done before next pass / B staging overwrites
    }

    // m1/m2 hold PACKED scores: low 10 mantissa bits = code id. m1 <= m2 invariant.
    float m1[8], m2[8];
#pragma unroll
    for (int i = 0; i < 8; ++i) { m1[i] = 3.4e38f; m2[i] = 3.4e38f; }

    float4v acc[2][4];
#pragma unroll
    for (int mt = 0; mt < 2; ++mt)
#pragma unroll
        for (int nt = 0; nt < 4; ++nt)
            acc[mt][nt] = (float4v){0.f, 0.f, 0.f, 0.f};

    auto epi = [&](int c) {
        const int jbase = c * 64 + col;
#pragma unroll
        for (int nt = 0; nt < 4; ++nt) {
            const unsigned jg = (unsigned)(jbase + nt * 16);
            const float ec = en_s[jg];
#pragma unroll
            for (int mt = 0; mt < 2; ++mt)
#pragma unroll
                for (int r = 0; r < 4; ++r) {
                    const int t = mt * 4 + r;
                    float s = fmaf(acc[mt][nt][r], -2.0f, ec);
                    // pack code id into low 10 mantissa bits (v_and_or_b32)
                    float p = __uint_as_float((__float_as_uint(s) & 0xFFFFFC00u) | jg);
                    // top-2 update in 2 instr: med3(m1,m2,p) = new second-min (m1<=m2)
                    m2[t] = __builtin_amdgcn_fmed3f(m1[t], m2[t], p);
                    m1[t] = fminf(m1[t], p);
                    acc[mt][nt][r] = 0.0f;
                }
        }
    };

    const unsigned char* wext = (const unsigned char*)outsrc;

    for (int c = 0; c < 16; ++c) {
        // async-stage B chunk c (64 codes x 384 B = 24576 B = exactly 6 loads/thread)
        {
            const unsigned char* gsrc = wext + c * 24576 + tid * 16;
            unsigned char*       ldst = smem + tid * 16;
#pragma unroll
            for (int it = 0; it < 6; ++it) {
                __builtin_amdgcn_global_load_lds(
                    (const __attribute__((address_space(1))) void*)(gsrc + it * 4096),
                    (__attribute__((address_space(3))) void*)(ldst + it * 4096),
                    16, 0, 0);
            }
        }
        if (c > 0) epi(c - 1);      // overlap previous epilogue with load latency
        __syncthreads();            // B chunk resident

#pragma unroll
        for (int ks = 0; ks < 6; ++ks) {
            short8 b[4];
#pragma unroll
            for (int nt = 0; nt < 4; ++nt)
                b[nt] = *(const short8*)(smem + ((nt * 6 + ks) * 64 + lane) * 16);
#pragma unroll
            for (int nt = 0; nt < 4; ++nt) {
                acc[0][nt] = __builtin_amdgcn_mfma_f32_16x16x32_bf16(afrag[0][ks], b[nt], acc[0][nt], 0, 0, 0);
                acc[1][nt] = __builtin_amdgcn_mfma_f32_16x16x32_bf16(afrag[1][ks], b[nt], acc[1][nt], 0, 0, 0);
            }
        }
        __syncthreads();            // all B reads done before next chunk's staging
    }
    epi(15);

    // ---- merge top-2 across the 16 C/D columns (lane bits 0..3).
    // Packed values are globally distinct (distinct code ids), so plain
    // min/second-min merge is exact; near-ties land within MARGIN -> flagged.
#pragma unroll
    for (int m = 1; m <= 8; m <<= 1) {
#pragma unroll
        for (int t = 0; t < 8; ++t) {
            float o1 = __shfl_xor(m1[t], m, 64);
            float o2 = __shfl_xor(m2[t], m, 64);
            m2[t] = fminf(fminf(m2[t], o2), fmaxf(m1[t], o1));
            m1[t] = fminf(m1[t], o1);
        }
    }
    if (col == 0) {
#pragma unroll
        for (int t = 0; t < 8; ++t) {
            const int mt = t >> 2, r = t & 3;
            const int tok = tokBase + wv * 32 + mt * 16 + quad * 4 + r;
            const int id  = (int)(__float_as_uint(m1[t]) & 1023u);
            idxf[tok] = (m2[t] - m1[t] < MARGIN) ? -(float)(id + 1) : (float)id;
        }
    }
}

// ---------------- K2: np-fp32-replicated rescan of flagged tokens (proven body)
__global__ __launch_bounds__(256) void k_recheck(
    const float* __restrict__ x, const float* __restrict__ w,
    float* __restrict__ idxf)
{
    __shared__ int   nflag;
    __shared__ int   flist[256];
    __shared__ float xf[DIM];
    __shared__ float rd[256];
    __shared__ int   rj[256];

    const int tid = threadIdx.x;
    const int tok = blockIdx.x * 256 + tid;
    if (tid == 0) nflag = 0;
    __syncthreads();
    if (idxf[tok] < 0.0f) { int p = atomicAdd(&nflag, 1); flist[p] = tok; }
    __syncthreads();
    const int nf = nflag;

    for (int f = 0; f < nf; ++f) {
        const int ft = flist[f];
        if (tid < DIM) xf[tid] = x[(size_t)ft * DIM + tid];
        __syncthreads();

        double xnd = 0.0;
        for (int k = 0; k < DIM; ++k) { double xv = (double)xf[k]; xnd += xv * xv; }
        const float xn = (float)xnd;

        float dbest = 3.4e38f; int jbest = 0;
#pragma unroll
        for (int jj = 0; jj < KCODES / 256; ++jj) {
            const int j = tid + jj * 256;
            const float* wr = w + (size_t)j * DIM;
            double end = 0.0;
            float  cacc = 0.0f;   // sequential-k fp32 FMA == BLAS sgemm microkernel
            for (int k = 0; k < DIM; ++k) {
                float wv2 = wr[k];
                end += (double)wv2 * wv2;
                cacc = __fmaf_rn(xf[k], wv2, cacc);
            }
            float T = __fadd_rn(xn, (float)end);
            float d = __fsub_rn(T, __fmul_rn(2.0f, cacc));
            if (d < dbest) { dbest = d; jbest = j; }   // strict <: first index
        }
        rd[tid] = dbest; rj[tid] = jbest;
        __syncthreads();
        for (int off = 128; off > 0; off >>= 1) {
            if (tid < off) {
                float od = rd[tid + off]; int oj = rj[tid + off];
                if (od < rd[tid] || (od == rd[tid] && oj < rj[tid])) {
                    rd[tid] = od; rj[tid] = oj;
                }
            }
            __syncthreads();
        }
        if (tid == 0) idxf[ft] = (float)rj[0];
        __syncthreads();
    }
}

// ---------------- K3: gather x_q + loss sum (reads final float idx)
__global__ __launch_bounds__(256) void k_gather(
    const float* __restrict__ x, const float* __restrict__ w,
    const float* __restrict__ idxf, float* __restrict__ out)
{
    const float4* x4 = (const float4*)x;
    const float4* w4 = (const float4*)w;
    float4*       o4 = (float4*)out;
    const int total4 = N_TOK * (DIM / 4);
    const int stride = gridDim.x * blockDim.x;
    double acc = 0.0;
    for (int i = blockIdx.x * blockDim.x + threadIdx.x; i < total4; i += stride) {
        int tok = i >> 4, c = i & 15;
        int id  = (int)idxf[tok];
        float4 xv = x4[i];
        float4 wv = w4[(size_t)id * (DIM / 4) + c];
        o4[i] = wv;
        float dx = xv.x - wv.x, dy = xv.y - wv.y, dz = xv.z - wv.z, dw = xv.w - wv.w;
        acc += (double)dx * dx + (double)dy * dy + (double)dz * dz + (double)dw * dw;
    }
    __shared__ double r[256];
    r[threadIdx.x] = acc;
    __syncthreads();
    for (int off = 128; off > 0; off >>= 1) {
        if (threadIdx.x < off) r[threadIdx.x] += r[threadIdx.x + off];
        __syncthreads();
    }
    if (threadIdx.x == 0) unsafeAtomicAdd(out + LOSS_POS, (float)r[0]);
}

// ---------------- K4: loss scale only
__global__ void k_loss(float* __restrict__ out) {
    out[LOSS_POS] = out[LOSS_POS] * 1.25f / 8388608.0f;
}

extern "C" void kernel_launch(void* const* d_in, const int* in_sizes, int n_in,
                              void* d_out, int out_size, void* d_ws, size_t ws_size,
                              hipStream_t stream) {
    const float* x = (const float*)d_in[0];
    const float* w = (const float*)d_in[1];
    float* out = (float*)d_out;
    float* idxf = out + LOSS_POS + 1;

    k_prep<<<100, 256, 0, stream>>>(w, out);
    k_screen<<<N_TOK / 128, 256, 0, stream>>>(x, out, idxf);
    k_recheck<<<N_TOK / 256, 256, 0, stream>>>(x, w, idxf);
    k_gather<<<2048, 256, 0, stream>>>(x, w, idxf, out);
    k_loss<<<1, 1, 0, stream>>>(out);
}

// Round 3
// 215.494 us; speedup vs baseline: 1.2743x; 1.0115x over previous
//
#include <hip/hip_runtime.h>

// VQ eval: x[131072,64] fp32, w[1024,64] fp32.
// out concat: x_q (8388608 f32) | loss (1 f32) | indices (131072 f32).
//
// Screen = bf16 MFMA GEMM, K=192 split trick: A_ext=[x_h|x_l|x_h], B_ext=[wm_h|wm_h|wm_l]
// where wm = -2*w (R11: -2 folded into B at prep time; exact x2 exponent shifts, same
// error budget). Score s = en[j] - 2*dot computed ENTIRELY by MFMA: acc is initialized
// to en[j] (C-operand accumulate-in), so the epilogue is just pack+med3+min.
// Top-2 gap < MARGIN -> idx written as -(id+1) (float); k_fix re-resolves flagged
// tokens with the np-fp32-replicated scan (sequential-k fp32 FMA == BLAS sgemm
// microkernel, quantized combine, first-index ties).
//
// R10: mantissa-packed argmin (id in low 10 mantissa bits; fmin+fmed3 top-2);
// packing perturbs scores <= 1023 ulp (~7.6e-6 at |s|<0.125), any affected token
// has packed gap < MARGIN -> flagged -> exact recheck. 65 us, VALUBusy 47 /
// MfmaUtil 34 / both pipes ~50% idle -> barrier-drain bound.
//
// R11: (a) double-buffered B staging, 32-code chunks: 2x12288 B buffers + en 4 KB
//      = 28672 B LDS (unchanged, 4 blocks/CU). One barrier per chunk; stage(c+1)
//      issued before compute(c) so the vmcnt(0) drain at the barrier is covered
//      by ds_read+MFMA+epi (~300+ cyc). Write-after-read safety: barrier at end of
//      iter c drains lgkm (all ds_reads of buf[c&1] done) before iter c+1's stage
//      overwrites it, and drains vmcnt (stage(c+1) landed) before iter c+1 reads.
//      (b) en-in-C + (-2)-in-B: epilogue 3 VALU/score.
//      (c) k_recheck+k_gather fused into k_fix (one launch less, idxf round-trip
//      via LDS, wave-parallel recheck).

#define N_TOK   131072
#define DIM     64
#define KCODES  1024
#define MARGIN  3e-5f
#define LOSS_POS ((size_t)8388608)
#define EN_OFF_F 98304           // w_ext = 98304 uints (32 chunks * 12 ksteps * 64 lanes * 4)

typedef __attribute__((ext_vector_type(8))) short  short8;
typedef __attribute__((ext_vector_type(4))) float  float4v;

__device__ __forceinline__ unsigned bf16rne(float f) {
    unsigned u = __float_as_uint(f);
    return (u + 0x7FFFu + ((u >> 16) & 1u)) >> 16;
}
__device__ __forceinline__ float bf16tof(unsigned h) { return __uint_as_float(h << 16); }

// ---------------- K0: w_ext = frag-ordered bf16 split of (-2w), 32-code chunks,
//                  + en[1024] + loss zero
__global__ __launch_bounds__(256) void k_prep(const float* __restrict__ w,
                                              float* __restrict__ out) {
    if (blockIdx.x < 96) {
        const int g    = blockIdx.x * 256 + threadIdx.x;   // 0..24575
        const int lane = g & 63;
        const int fs   = g >> 6;                            // c*12 + nt*6 + ks
        const int c = fs / 12, r = fs % 12, nt = r / 6, ks = r % 6;
        const int j    = c * 32 + nt * 16 + (lane & 15);    // 0..1023
        const int quad = lane >> 4;
        const int kk   = ks * 32 + quad * 8;                // 0..184
        const bool hi  = (kk < 128);
        const int k0   = hi ? (kk & 63) : (kk - 128);
        const float4* src = (const float4*)(w + (size_t)j * DIM + k0);
        float4 v0 = src[0], v1 = src[1];
        float f[8] = {-2.0f * v0.x, -2.0f * v0.y, -2.0f * v0.z, -2.0f * v0.w,
                      -2.0f * v1.x, -2.0f * v1.y, -2.0f * v1.z, -2.0f * v1.w};
        unsigned o[4];
#pragma unroll
        for (int p = 0; p < 4; ++p) {
            unsigned h0 = bf16rne(f[2 * p]), h1 = bf16rne(f[2 * p + 1]);
            if (hi) o[p] = h0 | (h1 << 16);
            else {
                unsigned l0 = bf16rne(f[2 * p]     - bf16tof(h0));
                unsigned l1 = bf16rne(f[2 * p + 1] - bf16tof(h1));
                o[p] = l0 | (l1 << 16);
            }
        }
        *(uint4*)((unsigned*)out + (size_t)g * 4) = make_uint4(o[0], o[1], o[2], o[3]);
    } else {
        const int row = (blockIdx.x - 96) * 256 + threadIdx.x;  // 0..1023
        const float* wr = w + (size_t)row * DIM;
        double en = 0.0;
#pragma unroll 8
        for (int k = 0; k < DIM; ++k) { double v = wr[k]; en += v * v; }
        out[EN_OFF_F + row] = (float)en;
        if (row == 0) out[LOSS_POS] = 0.0f;
    }
}

// ---------------- K1: MFMA screen + fused top-2, float idx out (negative = flagged)
__global__ __launch_bounds__(256, 4) void k_screen(
    const float* __restrict__ x, const float* __restrict__ outsrc,
    float* __restrict__ idxf)
{
    // [0,12288) buf0 | [12288,24576) buf1 | [24576,28672) en
    __shared__ __align__(16) unsigned char smem[28672];
    unsigned* smemU = (unsigned*)smem;
    const float* en_s = (const float*)(smem + 24576);

    const int tid  = threadIdx.x;
    const int lane = tid & 63;
    const int wv   = tid >> 6;
    const int col  = lane & 15;
    const int quad = (lane >> 4) & 3;
    const int tokBase = blockIdx.x * 128;

    // ---- stage en[1024] once (resident for the whole kernel)
    __builtin_amdgcn_global_load_lds(
        (const __attribute__((address_space(1))) void*)
            ((const unsigned char*)(outsrc + EN_OFF_F) + tid * 16),
        (__attribute__((address_space(3))) void*)(smem + 24576 + tid * 16),
        16, 0, 0);

    // ---- stage A_ext in two 64-token passes (uses [0,24576) scratch; afrag
    //      extracted before the region is reused as B buffers)
    short8 afrag[2][6];
    for (int pass = 0; pass < 2; ++pass) {
        const int row = tid >> 2, seg = tid & 3;
        const float4* xr = (const float4*)(x + (size_t)(tokBase + pass * 64 + row) * DIM + seg * 16);
        unsigned* rb = smemU + row * 96 + seg * 8;
#pragma unroll
        for (int q = 0; q < 4; ++q) {
            float4 v = xr[q];
            unsigned hx = bf16rne(v.x), hy = bf16rne(v.y);
            unsigned hz = bf16rne(v.z), hw = bf16rne(v.w);
            unsigned h01 = hx | (hy << 16), h23 = hz | (hw << 16);
            unsigned l01 = bf16rne(v.x - bf16tof(hx)) | (bf16rne(v.y - bf16tof(hy)) << 16);
            unsigned l23 = bf16rne(v.z - bf16tof(hz)) | (bf16rne(v.w - bf16tof(hw)) << 16);
            rb[2 * q] = h01;      rb[2 * q + 1] = h23;        // x_h  (k 0..63)
            rb[32 + 2 * q] = l01; rb[32 + 2 * q + 1] = l23;   // x_l  (k 64..127)
            rb[64 + 2 * q] = h01; rb[64 + 2 * q + 1] = h23;   // x_h  (k 128..191)
        }
        __syncthreads();
        if ((wv >> 1) == pass) {
#pragma unroll
            for (int mt = 0; mt < 2; ++mt)
#pragma unroll
                for (int ks = 0; ks < 6; ++ks)
                    afrag[mt][ks] = *(const short8*)(smem
                        + ((wv & 1) * 32 + mt * 16 + col) * 384 + ks * 64 + quad * 16);
        }
        __syncthreads();   // reads done before region reuse
    }

    // m1/m2 hold PACKED scores: low 10 mantissa bits = code id. m1 <= m2 invariant.
    float m1[8], m2[8];
#pragma unroll
    for (int i = 0; i < 8; ++i) { m1[i] = 3.4e38f; m2[i] = 3.4e38f; }

    // acc initialized to en[j] (chunk 0 columns); MFMA accumulates -2*dot on top.
    float4v acc[2][2];
    {
        const float e0 = en_s[col], e1 = en_s[16 + col];  // en resident (pass-0 barrier)
#pragma unroll
        for (int mt = 0; mt < 2; ++mt) {
            acc[mt][0] = (float4v){e0, e0, e0, e0};
            acc[mt][1] = (float4v){e1, e1, e1, e1};
        }
    }

    const unsigned char* wext = (const unsigned char*)outsrc;

    // ---- prologue: stage chunk 0 into buf0 (A region already consumed)
    {
        const unsigned char* gsrc = wext + tid * 16;
        unsigned char*       ldst = smem + tid * 16;
#pragma unroll
        for (int it = 0; it < 3; ++it)
            __builtin_amdgcn_global_load_lds(
                (const __attribute__((address_space(1))) void*)(gsrc + it * 4096),
                (__attribute__((address_space(3))) void*)(ldst + it * 4096),
                16, 0, 0);
    }
    __syncthreads();   // buf0 resident

    for (int c = 0; c < 32; ++c) {
        const int cur = c & 1;
        // issue next chunk's staging into the other buffer (latency hidden by compute)
        if (c < 31) {
            const unsigned char* gsrc = wext + (c + 1) * 12288 + tid * 16;
            unsigned char*       ldst = smem + (cur ^ 1) * 12288 + tid * 16;
#pragma unroll
            for (int it = 0; it < 3; ++it)
                __builtin_amdgcn_global_load_lds(
                    (const __attribute__((address_space(1))) void*)(gsrc + it * 4096),
                    (__attribute__((address_space(3))) void*)(ldst + it * 4096),
                    16, 0, 0);
        }

        // compute chunk c from buf[cur]
        const unsigned char* bbase = smem + cur * 12288 + (size_t)lane * 16;
#pragma unroll
        for (int ks = 0; ks < 6; ++ks) {
            short8 b0 = *(const short8*)(bbase + (ks)     * 1024);
            short8 b1 = *(const short8*)(bbase + (6 + ks) * 1024);
            acc[0][0] = __builtin_amdgcn_mfma_f32_16x16x32_bf16(afrag[0][ks], b0, acc[0][0], 0, 0, 0);
            acc[1][0] = __builtin_amdgcn_mfma_f32_16x16x32_bf16(afrag[1][ks], b0, acc[1][0], 0, 0, 0);
            acc[0][1] = __builtin_amdgcn_mfma_f32_16x16x32_bf16(afrag[0][ks], b1, acc[0][1], 0, 0, 0);
            acc[1][1] = __builtin_amdgcn_mfma_f32_16x16x32_bf16(afrag[1][ks], b1, acc[1][1], 0, 0, 0);
        }

        // epilogue chunk c: pack id, top-2 via med3+min; re-init acc to next chunk's en
        {
            float ecn0 = 0.0f, ecn1 = 0.0f;
            if (c < 31) {
                ecn0 = en_s[(c + 1) * 32 + col];
                ecn1 = en_s[(c + 1) * 32 + 16 + col];
            }
#pragma unroll
            for (int nt = 0; nt < 2; ++nt) {
                const unsigned jg = (unsigned)(c * 32 + nt * 16 + col);
                const float ecn = nt ? ecn1 : ecn0;
#pragma unroll
                for (int mt = 0; mt < 2; ++mt)
#pragma unroll
                    for (int r = 0; r < 4; ++r) {
                        const int t = mt * 4 + r;
                        float p = __uint_as_float((__float_as_uint(acc[mt][nt][r]) & 0xFFFFFC00u) | jg);
                        m2[t] = __builtin_amdgcn_fmed3f(m1[t], m2[t], p);
                        m1[t] = fminf(m1[t], p);
                        acc[mt][nt][r] = ecn;
                    }
            }
        }

        // one barrier per chunk: drains vmcnt (stage(c+1) landed) and lgkm (all
        // reads of buf[cur] done) -> iter c+1 may read buf[cur^1] and overwrite buf[cur].
        __syncthreads();
    }

    // ---- merge top-2 across the 16 C/D columns (lane bits 0..3).
    // Packed values are globally distinct (distinct code ids), so plain
    // min/second-min merge is exact; near-ties land within MARGIN -> flagged.
#pragma unroll
    for (int m = 1; m <= 8; m <<= 1) {
#pragma unroll
        for (int t = 0; t < 8; ++t) {
            float o1 = __shfl_xor(m1[t], m, 64);
            float o2 = __shfl_xor(m2[t], m, 64);
            m2[t] = fminf(fminf(m2[t], o2), fmaxf(m1[t], o1));
            m1[t] = fminf(m1[t], o1);
        }
    }
    if (col == 0) {
#pragma unroll
        for (int t = 0; t < 8; ++t) {
            const int mt = t >> 2, r = t & 3;
            const int tok = tokBase + wv * 32 + mt * 16 + quad * 4 + r;
            const int id  = (int)(__float_as_uint(m1[t]) & 1023u);
            idxf[tok] = (m2[t] - m1[t] < MARGIN) ? -(float)(id + 1) : (float)id;
        }
    }
}

// ---------------- K2: fused recheck (wave-parallel, np-fp32-replicated proven body)
//                  + gather x_q + loss sum for the block's 256 tokens
__global__ __launch_bounds__(256) void k_fix(
    const float* __restrict__ x, const float* __restrict__ w,
    float* __restrict__ idxf, float* __restrict__ out)
{
    __shared__ int   nflag;
    __shared__ int   flist[256];
    __shared__ float idxl[256];          // final index per local token (float)
    __shared__ float xs[4][DIM];         // per-wave x row for its current flagged token

    const int tid  = threadIdx.x;
    const int lane = tid & 63;
    const int wv   = tid >> 6;
    const int tokBase = blockIdx.x * 256;

    if (tid == 0) nflag = 0;
    __syncthreads();
    {
        float f0 = idxf[tokBase + tid];
        idxl[tid] = f0;
        if (f0 < 0.0f) { int p = atomicAdd(&nflag, 1); flist[p] = tid; }
    }
    __syncthreads();
    const int nf = nflag;

    // ---- phase 2: one wave per flagged token; lane scans 16 codes (j = lane + 64*jj,
    //      ascending -> strict < keeps first index within lane); cross-lane
    //      lexicographic (d, j) min == global first-index argmin.
    for (int i = wv; i < nf; i += 4) {
        const int ltid = flist[i];
        const int ft   = tokBase + ltid;
        xs[wv][lane] = x[(size_t)ft * DIM + lane];   // same-wave LDS RAW: compiler waits

        double xnd = 0.0;
        for (int k = 0; k < DIM; ++k) { double xv = (double)xs[wv][k]; xnd += xv * xv; }
        const float xn = (float)xnd;

        float dbest = 3.4e38f; int jbest = 0;
#pragma unroll 4
        for (int jj = 0; jj < KCODES / 64; ++jj) {
            const int j = lane + jj * 64;
            const float* wr = w + (size_t)j * DIM;
            double end = 0.0;
            float  cacc = 0.0f;   // sequential-k fp32 FMA == BLAS sgemm microkernel
            for (int k = 0; k < DIM; ++k) {
                float wv2 = wr[k];
                end += (double)wv2 * wv2;
                cacc = __fmaf_rn(xs[wv][k], wv2, cacc);
            }
            float T = __fadd_rn(xn, (float)end);
            float d = __fsub_rn(T, __fmul_rn(2.0f, cacc));
            if (d < dbest) { dbest = d; jbest = j; }   // strict <: first index in lane
        }
#pragma unroll
        for (int m = 1; m < 64; m <<= 1) {
            float od = __shfl_xor(dbest, m, 64);
            int   oj = __shfl_xor(jbest, m, 64);
            if (od < dbest || (od == dbest && oj < jbest)) { dbest = od; jbest = oj; }
        }
        if (lane == 0) {
            idxl[ltid] = (float)jbest;
            idxf[ft]   = (float)jbest;
        }
    }
    __syncthreads();   // idxl final for all 256 tokens

    // ---- phase 3: gather + loss (original proven k_gather body, idx from LDS)
    const float4* x4 = (const float4*)x;
    const float4* w4 = (const float4*)w;
    float4*       o4 = (float4*)out;
    double acc = 0.0;
#pragma unroll
    for (int k = 0; k < 16; ++k) {
        const int li = tid + k * 256;               // local float4 index [0,4096)
        const int i  = blockIdx.x * 4096 + li;
        const int id = (int)idxl[li >> 4];
        float4 xv = x4[i];
        float4 wvv = w4[(size_t)id * (DIM / 4) + (li & 15)];
        o4[i] = wvv;
        float dx = xv.x - wvv.x, dy = xv.y - wvv.y, dz = xv.z - wvv.z, dw = xv.w - wvv.w;
        acc += (double)dx * dx + (double)dy * dy + (double)dz * dz + (double)dw * dw;
    }
    __shared__ double rr[256];
    rr[tid] = acc;
    __syncthreads();
    for (int off = 128; off > 0; off >>= 1) {
        if (tid < off) rr[tid] += rr[tid + off];
        __syncthreads();
    }
    if (tid == 0) unsafeAtomicAdd(out + LOSS_POS, (float)rr[0]);
}

// ---------------- K3: loss scale only
__global__ void k_loss(float* __restrict__ out) {
    out[LOSS_POS] = out[LOSS_POS] * 1.25f / 8388608.0f;
}

extern "C" void kernel_launch(void* const* d_in, const int* in_sizes, int n_in,
                              void* d_out, int out_size, void* d_ws, size_t ws_size,
                              hipStream_t stream) {
    const float* x = (const float*)d_in[0];
    const float* w = (const float*)d_in[1];
    float* out = (float*)d_out;
    float* idxf = out + LOSS_POS + 1;

    k_prep<<<100, 256, 0, stream>>>(w, out);
    k_screen<<<N_TOK / 128, 256, 0, stream>>>(x, out, idxf);
    k_fix<<<N_TOK / 256, 256, 0, stream>>>(x, w, idxf, out);
    k_loss<<<1, 1, 0, stream>>>(out);
}

// Round 4
// 209.032 us; speedup vs baseline: 1.3137x; 1.0309x over previous
//
#include <hip/hip_runtime.h>

// VQ eval: x[131072,64] fp32, w[1024,64] fp32.
// out concat: x_q (8388608 f32) | loss (1 f32) | indices (131072 f32).
//
// Screen = bf16 MFMA GEMM, K=192 split trick: A_ext=[x_h|x_l|x_h], B_ext=[wm_h|wm_h|wm_l]
// where wm = -2*w (-2 folded into B at prep; exact x2 exponent shifts). Score
// s = en[j] - 2*dot computed ENTIRELY by MFMA: acc initialized to en[j] (C-operand
// accumulate-in), epilogue = pack+med3+min only. Top-2 gap < MARGIN -> idx written
// as -(id+1) (float); k_fix re-resolves flagged tokens with the np-fp32-replicated
// scan (sequential-k fp32 FMA == BLAS sgemm microkernel, quantized combine,
// first-index ties).
//
// R10: mantissa-packed argmin (id in low 10 mantissa bits; fmin+fmed3 top-2);
// packing perturbs scores <= 1023 ulp (~7.6e-6 at |s|<0.125), any affected token
// has packed gap < MARGIN -> flagged -> exact recheck.
// R11: double-buffered B staging (32-code chunks, one barrier/chunk), en-in-C,
// recheck+gather fused into k_fix.
// R12 lesson: k_fix at 512 blocks = 2 blocks/CU -> Occupancy 8.8%, latency-bound,
// 85 us for ~52 MB of traffic (ideal ~10 us). Regression vs the 2048-block
// separate gather. Fix: k_fix at 2048 blocks x 64 tokens (old gather shape),
// LDS ~3.6 KB, 8 blocks/CU.

#define N_TOK   131072
#define DIM     64
#define KCODES  1024
#define MARGIN  3e-5f
#define LOSS_POS ((size_t)8388608)
#define EN_OFF_F 98304           // w_ext = 98304 uints (32 chunks * 12 ksteps * 64 lanes * 4)

typedef __attribute__((ext_vector_type(8))) short  short8;
typedef __attribute__((ext_vector_type(4))) float  float4v;

__device__ __forceinline__ unsigned bf16rne(float f) {
    unsigned u = __float_as_uint(f);
    return (u + 0x7FFFu + ((u >> 16) & 1u)) >> 16;
}
__device__ __forceinline__ float bf16tof(unsigned h) { return __uint_as_float(h << 16); }

// ---------------- K0: w_ext = frag-ordered bf16 split of (-2w), 32-code chunks,
//                  + en[1024] + loss zero
__global__ __launch_bounds__(256) void k_prep(const float* __restrict__ w,
                                              float* __restrict__ out) {
    if (blockIdx.x < 96) {
        const int g    = blockIdx.x * 256 + threadIdx.x;   // 0..24575
        const int lane = g & 63;
        const int fs   = g >> 6;                            // c*12 + nt*6 + ks
        const int c = fs / 12, r = fs % 12, nt = r / 6, ks = r % 6;
        const int j    = c * 32 + nt * 16 + (lane & 15);    // 0..1023
        const int quad = lane >> 4;
        const int kk   = ks * 32 + quad * 8;                // 0..184
        const bool hi  = (kk < 128);
        const int k0   = hi ? (kk & 63) : (kk - 128);
        const float4* src = (const float4*)(w + (size_t)j * DIM + k0);
        float4 v0 = src[0], v1 = src[1];
        float f[8] = {-2.0f * v0.x, -2.0f * v0.y, -2.0f * v0.z, -2.0f * v0.w,
                      -2.0f * v1.x, -2.0f * v1.y, -2.0f * v1.z, -2.0f * v1.w};
        unsigned o[4];
#pragma unroll
        for (int p = 0; p < 4; ++p) {
            unsigned h0 = bf16rne(f[2 * p]), h1 = bf16rne(f[2 * p + 1]);
            if (hi) o[p] = h0 | (h1 << 16);
            else {
                unsigned l0 = bf16rne(f[2 * p]     - bf16tof(h0));
                unsigned l1 = bf16rne(f[2 * p + 1] - bf16tof(h1));
                o[p] = l0 | (l1 << 16);
            }
        }
        *(uint4*)((unsigned*)out + (size_t)g * 4) = make_uint4(o[0], o[1], o[2], o[3]);
    } else {
        const int row = (blockIdx.x - 96) * 256 + threadIdx.x;  // 0..1023
        const float* wr = w + (size_t)row * DIM;
        double en = 0.0;
#pragma unroll 8
        for (int k = 0; k < DIM; ++k) { double v = wr[k]; en += v * v; }
        out[EN_OFF_F + row] = (float)en;
        if (row == 0) out[LOSS_POS] = 0.0f;
    }
}

// ---------------- K1: MFMA screen + fused top-2, float idx out (negative = flagged)
__global__ __launch_bounds__(256, 4) void k_screen(
    const float* __restrict__ x, const float* __restrict__ outsrc,
    float* __restrict__ idxf)
{
    // [0,12288) buf0 | [12288,24576) buf1 | [24576,28672) en
    __shared__ __align__(16) unsigned char smem[28672];
    unsigned* smemU = (unsigned*)smem;
    const float* en_s = (const float*)(smem + 24576);

    const int tid  = threadIdx.x;
    const int lane = tid & 63;
    const int wv   = tid >> 6;
    const int col  = lane & 15;
    const int quad = (lane >> 4) & 3;
    const int tokBase = blockIdx.x * 128;

    // ---- stage en[1024] once (resident for the whole kernel)
    __builtin_amdgcn_global_load_lds(
        (const __attribute__((address_space(1))) void*)
            ((const unsigned char*)(outsrc + EN_OFF_F) + tid * 16),
        (__attribute__((address_space(3))) void*)(smem + 24576 + tid * 16),
        16, 0, 0);

    // ---- stage A_ext in two 64-token passes (uses [0,24576) scratch; afrag
    //      extracted before the region is reused as B buffers)
    short8 afrag[2][6];
    for (int pass = 0; pass < 2; ++pass) {
        const int row = tid >> 2, seg = tid & 3;
        const float4* xr = (const float4*)(x + (size_t)(tokBase + pass * 64 + row) * DIM + seg * 16);
        unsigned* rb = smemU + row * 96 + seg * 8;
#pragma unroll
        for (int q = 0; q < 4; ++q) {
            float4 v = xr[q];
            unsigned hx = bf16rne(v.x), hy = bf16rne(v.y);
            unsigned hz = bf16rne(v.z), hw = bf16rne(v.w);
            unsigned h01 = hx | (hy << 16), h23 = hz | (hw << 16);
            unsigned l01 = bf16rne(v.x - bf16tof(hx)) | (bf16rne(v.y - bf16tof(hy)) << 16);
            unsigned l23 = bf16rne(v.z - bf16tof(hz)) | (bf16rne(v.w - bf16tof(hw)) << 16);
            rb[2 * q] = h01;      rb[2 * q + 1] = h23;        // x_h  (k 0..63)
            rb[32 + 2 * q] = l01; rb[32 + 2 * q + 1] = l23;   // x_l  (k 64..127)
            rb[64 + 2 * q] = h01; rb[64 + 2 * q + 1] = h23;   // x_h  (k 128..191)
        }
        __syncthreads();
        if ((wv >> 1) == pass) {
#pragma unroll
            for (int mt = 0; mt < 2; ++mt)
#pragma unroll
                for (int ks = 0; ks < 6; ++ks)
                    afrag[mt][ks] = *(const short8*)(smem
                        + ((wv & 1) * 32 + mt * 16 + col) * 384 + ks * 64 + quad * 16);
        }
        __syncthreads();   // reads done before region reuse
    }

    // m1/m2 hold PACKED scores: low 10 mantissa bits = code id. m1 <= m2 invariant.
    float m1[8], m2[8];
#pragma unroll
    for (int i = 0; i < 8; ++i) { m1[i] = 3.4e38f; m2[i] = 3.4e38f; }

    // acc initialized to en[j] (chunk 0 columns); MFMA accumulates -2*dot on top.
    float4v acc[2][2];
    {
        const float e0 = en_s[col], e1 = en_s[16 + col];  // en resident (pass-0 barrier)
#pragma unroll
        for (int mt = 0; mt < 2; ++mt) {
            acc[mt][0] = (float4v){e0, e0, e0, e0};
            acc[mt][1] = (float4v){e1, e1, e1, e1};
        }
    }

    const unsigned char* wext = (const unsigned char*)outsrc;

    // ---- prologue: stage chunk 0 into buf0 (A region already consumed)
    {
        const unsigned char* gsrc = wext + tid * 16;
        unsigned char*       ldst = smem + tid * 16;
#pragma unroll
        for (int it = 0; it < 3; ++it)
            __builtin_amdgcn_global_load_lds(
                (const __attribute__((address_space(1))) void*)(gsrc + it * 4096),
                (__attribute__((address_space(3))) void*)(ldst + it * 4096),
                16, 0, 0);
    }
    __syncthreads();   // buf0 resident

    for (int c = 0; c < 32; ++c) {
        const int cur = c & 1;
        // issue next chunk's staging into the other buffer (latency hidden by compute)
        if (c < 31) {
            const unsigned char* gsrc = wext + (c + 1) * 12288 + tid * 16;
            unsigned char*       ldst = smem + (cur ^ 1) * 12288 + tid * 16;
#pragma unroll
            for (int it = 0; it < 3; ++it)
                __builtin_amdgcn_global_load_lds(
                    (const __attribute__((address_space(1))) void*)(gsrc + it * 4096),
                    (__attribute__((address_space(3))) void*)(ldst + it * 4096),
                    16, 0, 0);
        }

        // compute chunk c from buf[cur]
        const unsigned char* bbase = smem + cur * 12288 + (size_t)lane * 16;
#pragma unroll
        for (int ks = 0; ks < 6; ++ks) {
            short8 b0 = *(const short8*)(bbase + (ks)     * 1024);
            short8 b1 = *(const short8*)(bbase + (6 + ks) * 1024);
            acc[0][0] = __builtin_amdgcn_mfma_f32_16x16x32_bf16(afrag[0][ks], b0, acc[0][0], 0, 0, 0);
            acc[1][0] = __builtin_amdgcn_mfma_f32_16x16x32_bf16(afrag[1][ks], b0, acc[1][0], 0, 0, 0);
            acc[0][1] = __builtin_amdgcn_mfma_f32_16x16x32_bf16(afrag[0][ks], b1, acc[0][1], 0, 0, 0);
            acc[1][1] = __builtin_amdgcn_mfma_f32_16x16x32_bf16(afrag[1][ks], b1, acc[1][1], 0, 0, 0);
        }

        // epilogue chunk c: pack id, top-2 via med3+min; re-init acc to next chunk's en
        {
            float ecn0 = 0.0f, ecn1 = 0.0f;
            if (c < 31) {
                ecn0 = en_s[(c + 1) * 32 + col];
                ecn1 = en_s[(c + 1) * 32 + 16 + col];
            }
#pragma unroll
            for (int nt = 0; nt < 2; ++nt) {
                const unsigned jg = (unsigned)(c * 32 + nt * 16 + col);
                const float ecn = nt ? ecn1 : ecn0;
#pragma unroll
                for (int mt = 0; mt < 2; ++mt)
#pragma unroll
                    for (int r = 0; r < 4; ++r) {
                        const int t = mt * 4 + r;
                        float p = __uint_as_float((__float_as_uint(acc[mt][nt][r]) & 0xFFFFFC00u) | jg);
                        m2[t] = __builtin_amdgcn_fmed3f(m1[t], m2[t], p);
                        m1[t] = fminf(m1[t], p);
                        acc[mt][nt][r] = ecn;
                    }
            }
        }

        // one barrier per chunk: drains vmcnt (stage(c+1) landed) and lgkm (all
        // reads of buf[cur] done) -> iter c+1 may read buf[cur^1] and overwrite buf[cur].
        __syncthreads();
    }

    // ---- merge top-2 across the 16 C/D columns (lane bits 0..3).
    // Packed values are globally distinct (distinct code ids), so plain
    // min/second-min merge is exact; near-ties land within MARGIN -> flagged.
#pragma unroll
    for (int m = 1; m <= 8; m <<= 1) {
#pragma unroll
        for (int t = 0; t < 8; ++t) {
            float o1 = __shfl_xor(m1[t], m, 64);
            float o2 = __shfl_xor(m2[t], m, 64);
            m2[t] = fminf(fminf(m2[t], o2), fmaxf(m1[t], o1));
            m1[t] = fminf(m1[t], o1);
        }
    }
    if (col == 0) {
#pragma unroll
        for (int t = 0; t < 8; ++t) {
            const int mt = t >> 2, r = t & 3;
            const int tok = tokBase + wv * 32 + mt * 16 + quad * 4 + r;
            const int id  = (int)(__float_as_uint(m1[t]) & 1023u);
            idxf[tok] = (m2[t] - m1[t] < MARGIN) ? -(float)(id + 1) : (float)id;
        }
    }
}

// ---------------- K2: fused recheck + gather + loss, 64 tokens/block (2048 blocks)
__global__ __launch_bounds__(256) void k_fix(
    const float* __restrict__ x, const float* __restrict__ w,
    float* __restrict__ idxf, float* __restrict__ out)
{
    __shared__ int   nflag;
    __shared__ int   flist[64];
    __shared__ float idxl[64];           // final index per local token (float)
    __shared__ float xs[4][DIM];         // per-wave x row for its current flagged token

    const int tid  = threadIdx.x;
    const int lane = tid & 63;
    const int wv   = tid >> 6;
    const int tokBase = blockIdx.x * 64;

    if (tid == 0) nflag = 0;
    __syncthreads();
    if (tid < 64) {
        float f0 = idxf[tokBase + tid];
        idxl[tid] = f0;
        if (f0 < 0.0f) { int p = atomicAdd(&nflag, 1); flist[p] = tid; }
    }
    __syncthreads();
    const int nf = nflag;

    // ---- phase 2: one wave per flagged token; lane scans 16 codes (j = lane + 64*jj,
    //      ascending -> strict < keeps first index within lane); cross-lane
    //      lexicographic (d, j) min == global first-index argmin.
    for (int i = wv; i < nf; i += 4) {
        const int ltid = flist[i];
        const int ft   = tokBase + ltid;
        xs[wv][lane] = x[(size_t)ft * DIM + lane];   // same-wave LDS RAW: compiler waits

        double xnd = 0.0;
        for (int k = 0; k < DIM; ++k) { double xv = (double)xs[wv][k]; xnd += xv * xv; }
        const float xn = (float)xnd;

        float dbest = 3.4e38f; int jbest = 0;
#pragma unroll 4
        for (int jj = 0; jj < KCODES / 64; ++jj) {
            const int j = lane + jj * 64;
            const float* wr = w + (size_t)j * DIM;
            double end = 0.0;
            float  cacc = 0.0f;   // sequential-k fp32 FMA == BLAS sgemm microkernel
            for (int k = 0; k < DIM; ++k) {
                float wv2 = wr[k];
                end += (double)wv2 * wv2;
                cacc = __fmaf_rn(xs[wv][k], wv2, cacc);
            }
            float T = __fadd_rn(xn, (float)end);
            float d = __fsub_rn(T, __fmul_rn(2.0f, cacc));
            if (d < dbest) { dbest = d; jbest = j; }   // strict <: first index in lane
        }
#pragma unroll
        for (int m = 1; m < 64; m <<= 1) {
            float od = __shfl_xor(dbest, m, 64);
            int   oj = __shfl_xor(jbest, m, 64);
            if (od < dbest || (od == dbest && oj < jbest)) { dbest = od; jbest = oj; }
        }
        if (lane == 0) {
            idxl[ltid] = (float)jbest;
            idxf[ft]   = (float)jbest;
        }
    }
    __syncthreads();   // idxl final for all 64 tokens

    // ---- phase 3: gather + loss (proven body; idx from LDS; 4 float4/thread)
    const float4* x4 = (const float4*)x;
    const float4* w4 = (const float4*)w;
    float4*       o4 = (float4*)out;
    double acc = 0.0;
#pragma unroll
    for (int k = 0; k < 4; ++k) {
        const int li = tid + k * 256;               // local float4 index [0,1024)
        const int i  = blockIdx.x * 1024 + li;
        const int id = (int)idxl[li >> 4];
        float4 xv = x4[i];
        float4 wvv = w4[(size_t)id * (DIM / 4) + (li & 15)];
        o4[i] = wvv;
        float dx = xv.x - wvv.x, dy = xv.y - wvv.y, dz = xv.z - wvv.z, dw = xv.w - wvv.w;
        acc += (double)dx * dx + (double)dy * dy + (double)dz * dz + (double)dw * dw;
    }
    __shared__ double rr[256];
    rr[tid] = acc;
    __syncthreads();
    for (int off = 128; off > 0; off >>= 1) {
        if (tid < off) rr[tid] += rr[tid + off];
        __syncthreads();
    }
    if (tid == 0) unsafeAtomicAdd(out + LOSS_POS, (float)rr[0]);
}

// ---------------- K3: loss scale only
__global__ void k_loss(float* __restrict__ out) {
    out[LOSS_POS] = out[LOSS_POS] * 1.25f / 8388608.0f;
}

extern "C" void kernel_launch(void* const* d_in, const int* in_sizes, int n_in,
                              void* d_out, int out_size, void* d_ws, size_t ws_size,
                              hipStream_t stream) {
    const float* x = (const float*)d_in[0];
    const float* w = (const float*)d_in[1];
    float* out = (float*)d_out;
    float* idxf = out + LOSS_POS + 1;

    k_prep<<<100, 256, 0, stream>>>(w, out);
    k_screen<<<N_TOK / 128, 256, 0, stream>>>(x, out, idxf);
    k_fix<<<N_TOK / 64, 256, 0, stream>>>(x, w, idxf, out);
    k_loss<<<1, 1, 0, stream>>>(out);
}